// Round 1
// baseline (758.512 us; speedup 1.0000x reference)
//
#include <hip/hip_runtime.h>
#include <cfloat>
#include <math.h>

// Problem constants
constexpr int H_  = 6;
constexpr int C_  = 64;
constexpr int OV_ = 4;
constexpr int G_  = 3;
constexpr int NVQ_ = 6;
constexpr int K_  = 1024;
constexpr int D_  = 8;
constexpr int B_  = 32;
constexpr int W_  = 2400;
constexpr int T_  = 600;          // W/OV
constexpr int NPOS_ = B_ * T_;    // 19200
constexpr int FIX_ = H_ * C_;     // 384
constexpr int GD_ = 512;

// Output layout (floats, concatenated in return order)
constexpr size_t OUT_ZQ   = 0;
constexpr size_t OUT_IDX  = (size_t)B_ * H_ * W_ * C_;             // 29491200
constexpr size_t OUT_LOSS = OUT_IDX + (size_t)B_ * NVQ_ * G_ * T_; // 29836800

// Workspace layout (bytes)
constexpr size_t WS_EN   = 0;                                   // double[18432*8]
constexpr size_t WS_ZD   = WS_EN + (size_t)G_*NVQ_*K_*D_*8;     // double[3*19200*8]
constexpr size_t WS_LOSS = WS_ZD + (size_t)G_*NPOS_*D_*8;       // double[8]
constexpr size_t WS_ZQ   = WS_LOSS + 64;                        // float[3*19200*8]

// ---------------------------------------------------------------------------
// K1: normalize codebooks (fp64) into transposed layout en[(gi*8+d)*1024 + k];
//     also zero the loss accumulator.
__global__ __launch_bounds__(256) void k1_norm_cb(const float* __restrict__ cb,
                                                  double* __restrict__ en,
                                                  double* __restrict__ loss) {
    int tid = blockIdx.x * 256 + threadIdx.x;
    if (tid == 0) loss[0] = 0.0;
    if (tid >= G_ * NVQ_ * K_) return;
    int k  = tid & (K_ - 1);
    int gi = tid >> 10;               // 0..17  (g*6+i)
    const float* row = cb + ((size_t)gi * K_ + k) * D_;
    double v[D_];
    double ss = 0.0;
#pragma unroll
    for (int d = 0; d < D_; d++) { v[d] = (double)row[d]; ss += v[d] * v[d]; }
    double n = sqrt(ss);
    if (n < 1e-12) n = 1e-12;
#pragma unroll
    for (int d = 0; d < D_; d++)
        en[((size_t)gi * D_ + d) * K_ + k] = v[d] / n;   // division to mimic ref
}

// ---------------------------------------------------------------------------
// K2: fold (pre_process) + proj_down with fp64 accumulation.
// Block: 256 threads, 8 positions. LDS zfold layout: p*PSTR + ov*OVS + (c*6+h).
constexpr int PSTR_ = 1548;   // %32 = 12 -> 8 p's hit distinct banks; mult of 4
constexpr int OVS_  = 388;    // > 383; mult of 4

__global__ __launch_bounds__(256) void k2_fold_pd(const float* __restrict__ ze,
                                                  const float* __restrict__ pd,
                                                  double* __restrict__ zd) {
    __shared__ __align__(16) float zf[8 * PSTR_];    // ~49.5 KB
    int tid  = threadIdx.x;
    int pos0 = blockIdx.x * 8;
    // Load: 48 segments (p,h) x 256 contiguous floats; float4 per thread.
#pragma unroll
    for (int it = 0; it < 12; it++) {
        int slot = it * 256 + tid;      // 0..3071
        int seg  = slot >> 6;           // 0..47
        int li   = slot & 63;
        int p = seg / 6, h = seg - p * 6;
        int pos = pos0 + p;
        int b = pos / T_, t = pos - b * T_;
        const float4 vv = *(const float4*)(ze + ((size_t)((b * H_ + h) * W_ + 4 * t)) * C_ + li * 4);
        int ov = li >> 4;
        int c0 = (li & 15) * 4;
        int base = p * PSTR_ + ov * OVS_ + h;
        zf[base + (c0 + 0) * 6] = vv.x;
        zf[base + (c0 + 1) * 6] = vv.y;
        zf[base + (c0 + 2) * 6] = vv.z;
        zf[base + (c0 + 3) * 6] = vv.w;
    }
    __syncthreads();
    if (tid < 192) {
        int p = tid / 24;
        int combo = tid - p * 24;
        int g = combo >> 3, d = combo & 7;
        const float* pdp = pd + ((size_t)g * D_ + d) * GD_;
        int lbase = p * PSTR_;
        double acc = 0.0;
        for (int jj = 0; jj < GD_; jj += 4) {
            int gd  = g * GD_ + jj;
            int ov  = gd / FIX_;
            int rem = gd - ov * FIX_;          // always mult of 4; no ov straddle
            float4 zv = *(const float4*)&zf[lbase + ov * OVS_ + rem];
            float4 pv = *(const float4*)&pdp[jj];
            acc = fma((double)pv.x, (double)zv.x, acc);
            acc = fma((double)pv.y, (double)zv.y, acc);
            acc = fma((double)pv.z, (double)zv.z, acc);
            acc = fma((double)pv.w, (double)zv.w, acc);
        }
        zd[((size_t)g * NPOS_ + pos0 + p) * D_ + d] = acc;
    }
}

// ---------------------------------------------------------------------------
// K3: residual VQ, 6 streams, full fp64. Block: 512 threads (8 waves), one
// group, 32 positions (4 chains per wave). Codebook (fp64, transposed) staged
// in 64 KB LDS per stream; lane <-> codeword k = j*64+lane (b64 reads,
// conflict-free); butterfly argmax with first-index tie-break.
__global__ __launch_bounds__(512) void k3_rvq(const double* __restrict__ en_g,
                                              const double* __restrict__ zd,
                                              float* __restrict__ zq,
                                              double* __restrict__ loss,
                                              float* __restrict__ out_idx) {
    __shared__ __align__(16) double en_s[D_ * K_];   // 64 KB
    __shared__ double zd_s[8 * 32];                  // 2 KB
    __shared__ double ls[8];
    int tid  = threadIdx.x;
    int wv   = tid >> 6, lane = tid & 63;
    int g     = blockIdx.x / 600;
    int chunk = blockIdx.x - g * 600;
    int pos0  = chunk * 32;
    int mypos0 = pos0 + wv * 4;
    size_t zdbase = ((size_t)g * NPOS_ + mypos0) * D_;
    if (lane < 32) zd_s[wv * 32 + lane] = zd[zdbase + lane];
    double r[4][8];
#pragma unroll
    for (int m = 0; m < 4; m++)
#pragma unroll
        for (int d = 0; d < 8; d++) r[m][d] = zd[zdbase + m * 8 + d];
    double loss_acc = 0.0;

    for (int i = 0; i < NVQ_; i++) {
        __syncthreads();
        const double* src = en_g + ((size_t)(g * NVQ_ + i)) * D_ * K_;
#pragma unroll
        for (int it = 0; it < 8; it++) {
            int idx = it * 512 + tid;   // 4096 double2 = 8192 doubles
            ((double2*)en_s)[idx] = ((const double2*)src)[idx];
        }
        __syncthreads();

        double smax[4]; int sidx[4];
#pragma unroll
        for (int m = 0; m < 4; m++) { smax[m] = -DBL_MAX; sidx[m] = 0; }
        for (int j = 0; j < 16; j++) {
            int k = j * 64 + lane;
            double cw[8];
#pragma unroll
            for (int d = 0; d < 8; d++) cw[d] = en_s[d * K_ + k];
#pragma unroll
            for (int m = 0; m < 4; m++) {
                double s = 0.0;
#pragma unroll
                for (int d = 0; d < 8; d++) s = fma(cw[d], r[m][d], s);
                if (s > smax[m]) { smax[m] = s; sidx[m] = k; }   // strict >: keeps first
            }
        }
#pragma unroll
        for (int off = 32; off >= 1; off >>= 1) {
#pragma unroll
            for (int m = 0; m < 4; m++) {
                double om = __shfl_xor(smax[m], off);
                int    oi = __shfl_xor(sidx[m], off);
                if (om > smax[m] || (om == smax[m] && oi < sidx[m])) { smax[m] = om; sidx[m] = oi; }
            }
        }
#pragma unroll
        for (int m = 0; m < 4; m++) {
            int code = sidx[m];
#pragma unroll
            for (int d = 0; d < 8; d++) {
                double q = en_s[d * K_ + code];   // broadcast read
                r[m][d] -= q;
                loss_acc = fma(r[m][d], r[m][d], loss_acc);
            }
            if (lane == 0) {
                int pos = mypos0 + m;
                int b = pos / T_, t = pos - b * T_;
                out_idx[((size_t)(b * NVQ_ + i) * G_ + g) * T_ + t] = (float)code;
            }
        }
    }
    // zq = zd - r_final; funnel replicated regs to lanes 0..31 for one coalesced store
    double val = 0.0;
#pragma unroll
    for (int m = 0; m < 4; m++)
#pragma unroll
        for (int d = 0; d < 8; d++) {
            double z = zd_s[wv * 32 + m * 8 + d] - r[m][d];
            if (lane == m * 8 + d) val = z;
        }
    if (lane < 32) zq[zdbase + lane] = (float)val;
    // loss: per-block reduce, one fp64 atomic
    if (lane == 0) ls[wv] = loss_acc;
    __syncthreads();
    if (tid == 0) {
        double s = 0.0;
#pragma unroll
        for (int w2 = 0; w2 < 8; w2++) s += ls[w2];
        atomicAdd(loss, s);
    }
}

// ---------------------------------------------------------------------------
// K4: proj_up + unfold scatter (fp32 is sufficient: 2% threshold). Block: 256
// threads, 4 positions (1/wave). pu staged in LDS with stride-9 rows to break
// the 16-way bank conflict of the natural stride-8 gather. Also writes losses.
__global__ __launch_bounds__(256) void k4_up(const float* __restrict__ zq,
                                             const float* __restrict__ pu,
                                             const double* __restrict__ loss,
                                             float* __restrict__ out_zq,
                                             float* __restrict__ out_loss) {
    __shared__ __align__(16) float pu_s[G_ * GD_ * 9];   // 54 KB, row stride 9
    int tid = threadIdx.x;
#pragma unroll
    for (int it = 0; it < 6; it++) {
        int row = it * 256 + tid;            // 0..1535
        float4 lo = *(const float4*)(pu + (size_t)row * 8);
        float4 hi = *(const float4*)(pu + (size_t)row * 8 + 4);
        float* dst = &pu_s[row * 9];
        dst[0] = lo.x; dst[1] = lo.y; dst[2] = lo.z; dst[3] = lo.w;
        dst[4] = hi.x; dst[5] = hi.y; dst[6] = hi.z; dst[7] = hi.w;
    }
    if (blockIdx.x == 0 && tid == 0) {
        double l = loss[0] * (1.0 / 460800.0);   // /(B*T*D) per group, /G
        out_loss[0] = (float)l;
        out_loss[1] = (float)l;
    }
    __syncthreads();
    int wv = tid >> 6, lane = tid & 63;
    int pos = blockIdx.x * 4 + wv;
    int b = pos / T_, t = pos - b * T_;
    int ov = lane >> 4, c0 = (lane & 15) * 4;
    // A lane's 24 outputs span gd range [gd_min, gd_min+23]: at most 2 groups.
    int gd_min = ov * FIX_ + c0 * 6;
    int g_lo = gd_min >> 9;
    int g_hi = g_lo < 2 ? g_lo + 1 : 2;
    float za[8], zb[8];
    const float* zqa = zq + ((size_t)g_lo * NPOS_ + pos) * D_;
    const float* zqb = zq + ((size_t)g_hi * NPOS_ + pos) * D_;
#pragma unroll
    for (int d = 0; d < 8; d++) { za[d] = zqa[d]; zb[d] = zqb[d]; }
#pragma unroll
    for (int h = 0; h < H_; h++) {
        float4 o;
        float* op = &o.x;
#pragma unroll
        for (int q = 0; q < 4; q++) {
            int gd = ov * FIX_ + (c0 + q) * 6 + h;
            int g  = gd >> 9;
            int j  = gd & 511;
            const float* pr = &pu_s[(g * GD_ + j) * 9];
            bool hi = (g != g_lo);
            float acc = 0.f;
#pragma unroll
            for (int d = 0; d < 8; d++) {
                float zv = hi ? zb[d] : za[d];
                acc = fmaf(zv, pr[d], acc);
            }
            op[q] = acc;
        }
        *(float4*)(out_zq + ((size_t)((b * H_ + h) * W_ + 4 * t + ov)) * C_ + c0) = o;
    }
}

// ---------------------------------------------------------------------------
extern "C" void kernel_launch(void* const* d_in, const int* in_sizes, int n_in,
                              void* d_out, int out_size, void* d_ws, size_t ws_size,
                              hipStream_t stream) {
    const float* ze = (const float*)d_in[0];
    const float* pd = (const float*)d_in[1];
    const float* pu = (const float*)d_in[2];
    const float* cb = (const float*)d_in[3];
    // d_in[4] = num_streams (==6, compile-time NVQ_)

    float* out = (float*)d_out;
    char*  ws  = (char*)d_ws;
    double* ws_en   = (double*)(ws + WS_EN);
    double* ws_zd   = (double*)(ws + WS_ZD);
    double* ws_loss = (double*)(ws + WS_LOSS);
    float*  ws_zq   = (float*)(ws + WS_ZQ);

    k1_norm_cb<<<(G_ * NVQ_ * K_ + 255) / 256, 256, 0, stream>>>(cb, ws_en, ws_loss);
    k2_fold_pd<<<NPOS_ / 8, 256, 0, stream>>>(ze, pd, ws_zd);
    k3_rvq<<<G_ * (NPOS_ / 32), 512, 0, stream>>>(ws_en, ws_zd, ws_zq, ws_loss, out + OUT_IDX);
    k4_up<<<NPOS_ / 4, 256, 0, stream>>>(ws_zq, pu, ws_loss, out + OUT_ZQ, out + OUT_LOSS);
}